// Round 11
// baseline (3853.597 us; speedup 1.0000x reference)
//
#include <hip/hip_runtime.h>
#include <math.h>

#define B_ 8
#define N_ 2048
#define H_ 128
#define BN_ (B_ * N_)

// ws layout: A [BN][H] f32 | C [BN][H] f32 | K [B][N][N] u32 (sortable keys)
// need = 2*8MB + 128MB = 150,994,944 bytes

typedef float f4v __attribute__((ext_vector_type(4)));

__device__ __forceinline__ float elu1(float x) {
    return x > 0.f ? x : (__expf(x) - 1.f);
}

// Order-preserving bijection f32 -> u32 (exact inverse). Finite floats never map to 0.
__device__ __forceinline__ unsigned enc_key(float v) {
    unsigned u = __float_as_uint(v);
    return (u & 0x80000000u) ? ~u : (u | 0x80000000u);
}
__device__ __forceinline__ float dec_key(unsigned k) {
    return __uint_as_float((k & 0x80000000u) ? (k & 0x7FFFFFFFu) : ~k);
}

// ---------------- K1: A = emb@W1[:H] ; C = emb@W1[H:] + b1 ----------------
// NUMERICS FROZEN (passed absmax=0 x8) — do not reorder the fma chain.
__global__ __launch_bounds__(H_) void k_ac(const float* __restrict__ emb,
                                           const float* __restrict__ W1,
                                           const float* __restrict__ b1,
                                           float* __restrict__ A,
                                           float* __restrict__ C) {
    __shared__ float e[H_];
    const int i = blockIdx.x;
    const int k = threadIdx.x;
    e[k] = emb[(size_t)i * H_ + k];
    __syncthreads();
    float a = 0.f, c = 0.f;
#pragma unroll 8
    for (int h = 0; h < H_; ++h) {
        const float ev = e[h];
        a = fmaf(ev, W1[h * H_ + k], a);
        c = fmaf(ev, W1[(H_ + h) * H_ + k], c);
    }
    A[(size_t)i * H_ + k] = a;
    C[(size_t)i * H_ + k] = c + b1[k];
}

// ---------------- K2: K[g][i][j] = enc_key(w2 . elu(A_i + C_j) + b2) -------
// z NUMERICS FROZEN: per-value op sequence identical to r1-r9 (8-fma chain in
// h order, then shfl_xor 4/8/16/32, then +b2). C loads are NON-TEMPORAL
// (pure cache hint, bit-identical data) so the 1-2 GB C stream doesn't evict
// K rows from L3 before k_path reads them once each.
__global__ __launch_bounds__(256) void k_z(const float* __restrict__ A,
                                           const float* __restrict__ Cc,
                                           const float* __restrict__ w2,
                                           const float* __restrict__ b2p,
                                           unsigned* __restrict__ K) {
    const int lane = threadIdx.x & 63;
    const int wave = threadIdx.x >> 6;          // 0..3
    const int g = blockIdx.x >> 8;              // 256 blocks per graph
    const int sub = blockIdx.x & 255;
    const int rowtile = sub & 127;
    const int jh = sub >> 7;
    const int ibase = rowtile * 16 + wave * 4;
    const int i = ibase + (lane & 3);           // this group's row
    const int he = (lane >> 2) * 8;             // h-slice start (0..120)
    const float b2v = *b2p;

    const float* Arow = A + ((size_t)g * N_ + i) * H_ + he;
    const float4 a0 = *(const float4*)(Arow);
    const float4 a1 = *(const float4*)(Arow + 4);
    const float4 w0 = *(const float4*)(w2 + he);
    const float4 w1v = *(const float4*)(w2 + he + 4);
    const float* Cg = Cc + (size_t)g * N_ * H_ + he;
    unsigned* Krow = K + ((size_t)g * N_ + i) * N_;
    const bool writer = ((lane >> 2) == 0);

    const int j0 = jh * 1024;
    for (int j = j0; j < j0 + 1024; j += 8) {
        f4v c0[8], c1[8];
#pragma unroll
        for (int q = 0; q < 8; ++q) {
            const float* Cj = Cg + (size_t)(j + q) * H_;
            c0[q] = __builtin_nontemporal_load((const f4v*)(Cj));
            c1[q] = __builtin_nontemporal_load((const f4v*)(Cj + 4));
        }
        float pv[8];
#pragma unroll
        for (int q = 0; q < 8; ++q) {
            float p = 0.f;
            p = fmaf(w0.x, elu1(a0.x + c0[q].x), p);
            p = fmaf(w0.y, elu1(a0.y + c0[q].y), p);
            p = fmaf(w0.z, elu1(a0.z + c0[q].z), p);
            p = fmaf(w0.w, elu1(a0.w + c0[q].w), p);
            p = fmaf(w1v.x, elu1(a1.x + c1[q].x), p);
            p = fmaf(w1v.y, elu1(a1.y + c1[q].y), p);
            p = fmaf(w1v.z, elu1(a1.z + c1[q].z), p);
            p = fmaf(w1v.w, elu1(a1.w + c1[q].w), p);
            pv[q] = p;
        }
        // 8 independent shuffle-reduce chains (same per-value order as r1-r9)
#pragma unroll
        for (int q = 0; q < 8; ++q) pv[q] += __shfl_xor(pv[q], 4);
#pragma unroll
        for (int q = 0; q < 8; ++q) pv[q] += __shfl_xor(pv[q], 8);
#pragma unroll
        for (int q = 0; q < 8; ++q) pv[q] += __shfl_xor(pv[q], 16);
#pragma unroll
        for (int q = 0; q < 8; ++q) pv[q] += __shfl_xor(pv[q], 32);
        if (writer) {
            uint4 ka, kb;
            ka.x = enc_key(pv[0] + b2v);
            ka.y = enc_key(pv[1] + b2v);
            ka.z = enc_key(pv[2] + b2v);
            ka.w = enc_key(pv[3] + b2v);
            kb.x = enc_key(pv[4] + b2v);
            kb.y = enc_key(pv[5] + b2v);
            kb.z = enc_key(pv[6] + b2v);
            kb.w = enc_key(pv[7] + b2v);
            *(uint4*)(Krow + j) = ka;
            *(uint4*)(Krow + j + 4) = kb;
        }
    }
}

// ---------------- K3: greedy chain — 256-thread walker, shallow reduce -----
// Thread tid owns slots j = 8*tid .. 8*tid+7 (two uint4 loads). Visited mask
// = 8-bit register. Reduce: depth-3 in-lane tree (strict > keeps min j) ->
// 6-round lexicographic wave butterfly -> one barrier -> every thread folds
// the 4 wave partials from LDS (parity double-buffered; no 2nd barrier).
// Next-row loads issue before sigmoid/break so HBM/L3 latency overlaps them.
__global__ __launch_bounds__(256) void k_path7(const float* __restrict__ emb,
                                               const unsigned* __restrict__ K,
                                               float* __restrict__ out) {
    const int g = blockIdx.x;
    const int tid = threadIdx.x;       // 0..255
    const int lane = tid & 63;
    const int wid = tid >> 6;          // 0..3

    __shared__ unsigned swv[2][4];
    __shared__ int swj[2][4];
    __shared__ int s_root;

    float* pathOut = out + (size_t)g * N_;
    float* scoreOut = out + (size_t)BN_ + (size_t)g * N_;

    // root = argmax_j emb[g][j][0], first-max tie-break (wave 0 only)
    if (tid < 64) {
        float bv0 = -INFINITY;
        int bi0 = 0x7fffffff;
        for (int j = lane; j < N_; j += 64) {
            const float v = emb[((size_t)g * N_ + j) * H_];
            if (v > bv0) { bv0 = v; bi0 = j; }  // ascending j => first max
        }
#pragma unroll
        for (int off = 1; off < 64; off <<= 1) {
            const float ov = __shfl_xor(bv0, off);
            const int oi = __shfl_xor(bi0, off);
            if (ov > bv0 || (ov == bv0 && oi < bi0)) { bv0 = ov; bi0 = oi; }
        }
        if (lane == 0) {
            s_root = bi0;
            pathOut[0] = (float)bi0;
            scoreOut[0] = 1.0f;
        }
    }
    __syncthreads();

    int cur = s_root;
    unsigned vb = 0;
    if ((cur >> 3) == tid) vb |= 1u << (cur & 7);

    const unsigned* Kg = K + (size_t)g * N_ * N_;
    uint4 k0, k1;
    {
        const uint4* p = (const uint4*)(Kg + ((size_t)cur << 11) + (tid << 3));
        k0 = p[0];
        k1 = p[1];
    }

    int par = 0;
    int t = 1;
    for (; t < N_; ++t) {
        // mask visited -> 0 (finite keys never 0)
        const unsigned v0 = (vb & 1u)   ? 0u : k0.x;
        const unsigned v1 = (vb & 2u)   ? 0u : k0.y;
        const unsigned v2 = (vb & 4u)   ? 0u : k0.z;
        const unsigned v3 = (vb & 8u)   ? 0u : k0.w;
        const unsigned v4 = (vb & 16u)  ? 0u : k1.x;
        const unsigned v5 = (vb & 32u)  ? 0u : k1.y;
        const unsigned v6 = (vb & 64u)  ? 0u : k1.z;
        const unsigned v7 = (vb & 128u) ? 0u : k1.w;

        // depth-3 tree; strict > keeps the lower slot (min j) on ties
        unsigned va = v0; int ja = 0;
        if (v1 > va) { va = v1; ja = 1; }
        unsigned vbp = v2; int jb = 2;
        if (v3 > vbp) { vbp = v3; jb = 3; }
        unsigned vc = v4; int jc = 4;
        if (v5 > vc) { vc = v5; jc = 5; }
        unsigned vd = v6; int jd = 6;
        if (v7 > vd) { vd = v7; jd = 7; }
        if (vbp > va) { va = vbp; ja = jb; }
        if (vd > vc) { vc = vd; jc = jd; }
        if (vc > va) { va = vc; ja = jc; }
        unsigned wv_ = va;
        int wj_ = (tid << 3) | ja;

        // 6-round lexicographic wave butterfly: (max key, min j)
#pragma unroll
        for (int off = 1; off < 64; off <<= 1) {
            const unsigned ov = __shfl_xor(wv_, off);
            const int oj = __shfl_xor(wj_, off);
            if (ov > wv_ || (ov == wv_ && oj < wj_)) { wv_ = ov; wj_ = oj; }
        }
        if (lane == 0) {
            swv[par][wid] = wv_;
            swj[par][wid] = wj_;
        }
        __syncthreads();

        // serial-redundant fold of the 4 wave partials (every thread)
        unsigned fv = swv[par][0];
        int fj = swj[par][0];
#pragma unroll
        for (int w = 1; w < 4; ++w) {
            const unsigned nv = swv[par][w];
            const int nj = swj[par][w];
            if (nv > fv || (nv == fv && nj < fj)) { fv = nv; fj = nj; }
        }
        const int bi = fj;

        // issue next row's loads NOW; sigmoid/break/bookkeeping overlap them
        uint4 n0, n1;
        {
            const uint4* p = (const uint4*)(Kg + ((size_t)bi << 11) + (tid << 3));
            n0 = p[0];
            n1 = p[1];
        }

        const float bv = dec_key(fv);
        const float s = 1.f / (1.f + expf(-bv));
        if (!((double)s > 0.3)) break;  // frozen break form (passed r1-r9)
        if ((bi >> 3) == tid) vb |= 1u << (bi & 7);
        if (tid == 0) {
            pathOut[t] = (float)bi;
            scoreOut[t] = s;
        }
        k0 = n0;
        k1 = n1;
        par ^= 1;
    }
    for (int tt = t + tid; tt < N_; tt += 256) {
        pathOut[tt] = -1.f;
        scoreOut[tt] = 0.f;
    }
}

// ---------------- Fallback: on-the-fly scoring (ws too small for K) --------
__device__ __forceinline__ void blockArgmax(float& bv, int& bi, float* rv, int* ri,
                                            int lane, int wid, int nw) {
#pragma unroll
    for (int off = 1; off < 64; off <<= 1) {
        const float ov = __shfl_xor(bv, off);
        const int oi = __shfl_xor(bi, off);
        if (ov > bv || (ov == bv && oi < bi)) { bv = ov; bi = oi; }
    }
    if (lane == 0) { rv[wid] = bv; ri[wid] = bi; }
    __syncthreads();
    if (wid == 0) {
        float v = (lane < nw) ? rv[lane] : -INFINITY;
        int ix = (lane < nw) ? ri[lane] : 0x7fffffff;
#pragma unroll
        for (int off = 1; off < 16; off <<= 1) {
            const float ov = __shfl_xor(v, off);
            const int oi = __shfl_xor(ix, off);
            if (ov > v || (ov == v && oi < ix)) { v = ov; ix = oi; }
        }
        if (lane == 0) { rv[0] = v; ri[0] = ix; }
    }
    __syncthreads();
    bv = rv[0];
    bi = ri[0];
}

__global__ __launch_bounds__(1024) void k_path_fly(const float* __restrict__ emb,
                                                   const float* __restrict__ A,
                                                   const float* __restrict__ Cc,
                                                   const float* __restrict__ w2g,
                                                   const float* __restrict__ b2p,
                                                   float* __restrict__ out) {
    const int g = blockIdx.x;
    const int tid = threadIdx.x;
    const int lane = tid & 63, wid = tid >> 6;
    __shared__ float acur[H_], w2s[H_];
    __shared__ unsigned char vis[N_];
    __shared__ float rv[16];
    __shared__ int ri[16];
    const float b2v = *b2p;
    if (tid < H_) w2s[tid] = w2g[tid];
    for (int j = tid; j < N_; j += 1024) vis[j] = 0;

    float bv = -INFINITY;
    int bi = 0x7fffffff;
    for (int j = tid; j < N_; j += 1024) {
        const float v = emb[((size_t)g * N_ + j) * H_];
        if (v > bv) { bv = v; bi = j; }
    }
    __syncthreads();
    blockArgmax(bv, bi, rv, ri, lane, wid, 16);
    int cur = bi;
    float* pathOut = out + (size_t)g * N_;
    float* scoreOut = out + (size_t)BN_ + (size_t)g * N_;
    if (tid == 0) {
        vis[cur] = 1;
        pathOut[0] = (float)cur;
        scoreOut[0] = 1.0f;
    }
    __syncthreads();

    int t = 1;
    for (; t < N_; ++t) {
        if (tid < H_) acur[tid] = A[((size_t)g * N_ + cur) * H_ + tid];
        __syncthreads();
        float mbv = -INFINITY;
        int mbi = 0x7fffffff;
#pragma unroll
        for (int q = 0; q < 2; ++q) {
            const int j = tid + q * 1024;
            const float* Cj = Cc + ((size_t)g * N_ + j) * H_;
            float p = 0.f;
            for (int h = 0; h < H_; h += 4) {
                const float4 c = *(const float4*)(Cj + h);
                p = fmaf(w2s[h + 0], elu1(acur[h + 0] + c.x), p);
                p = fmaf(w2s[h + 1], elu1(acur[h + 1] + c.y), p);
                p = fmaf(w2s[h + 2], elu1(acur[h + 2] + c.z), p);
                p = fmaf(w2s[h + 3], elu1(acur[h + 3] + c.w), p);
            }
            const float z = p + b2v;
            if (!vis[j] && (z > mbv || (z == mbv && j < mbi))) { mbv = z; mbi = j; }
        }
        __syncthreads();
        blockArgmax(mbv, mbi, rv, ri, lane, wid, 16);
        const float s = 1.f / (1.f + expf(-mbv));
        if (!((double)s > 0.3)) break;
        cur = mbi;
        if (tid == 0) {
            vis[cur] = 1;
            pathOut[t] = (float)cur;
            scoreOut[t] = s;
        }
        __syncthreads();
    }
    for (int tt = t + tid; tt < N_; tt += 1024) {
        pathOut[tt] = -1.f;
        scoreOut[tt] = 0.f;
    }
}

extern "C" void kernel_launch(void* const* d_in, const int* in_sizes, int n_in,
                              void* d_out, int out_size, void* d_ws, size_t ws_size,
                              hipStream_t stream) {
    (void)in_sizes; (void)n_in; (void)out_size;
    const float* emb = (const float*)d_in[0];
    // d_in[1] = batch (int64) — contiguous equal-sized graphs, unused
    const float* W1 = (const float*)d_in[2];
    const float* b1 = (const float*)d_in[3];
    const float* w2 = (const float*)d_in[4];
    const float* b2 = (const float*)d_in[5];
    float* out = (float*)d_out;

    float* A = (float*)d_ws;
    float* C = A + (size_t)BN_ * H_;
    unsigned* K = (unsigned*)(C + (size_t)BN_ * H_);
    const size_t need = ((size_t)BN_ * H_ * 2 + (size_t)B_ * N_ * N_) * sizeof(float);

    hipLaunchKernelGGL(k_ac, dim3(BN_), dim3(H_), 0, stream, emb, W1, b1, A, C);
    if (ws_size >= need) {
        hipLaunchKernelGGL(k_z, dim3(2048), dim3(256), 0, stream, A, C, w2, b2, K);
        hipLaunchKernelGGL(k_path7, dim3(B_), dim3(256), 0, stream, emb, K, out);
    } else {
        hipLaunchKernelGGL(k_path_fly, dim3(B_), dim3(1024), 0, stream,
                           emb, A, C, w2, b2, out);
    }
}

// Round 12
// 3849.516 us; speedup vs baseline: 1.0011x; 1.0011x over previous
//
#include <hip/hip_runtime.h>
#include <math.h>

#define B_ 8
#define N_ 2048
#define H_ 128
#define BN_ (B_ * N_)

// ws layout: A [BN][H] f32 | C [BN][H] f32 | K [B][N][N] u32 (sortable keys)
// need = 2*8MB + 128MB = 150,994,944 bytes

typedef float f4v __attribute__((ext_vector_type(4)));

__device__ __forceinline__ float elu1(float x) {
    return x > 0.f ? x : (__expf(x) - 1.f);
}

// Order-preserving bijection f32 -> u32 (exact inverse). Finite floats never map to 0.
__device__ __forceinline__ unsigned enc_key(float v) {
    unsigned u = __float_as_uint(v);
    return (u & 0x80000000u) ? ~u : (u | 0x80000000u);
}
__device__ __forceinline__ float dec_key(unsigned k) {
    return __uint_as_float((k & 0x80000000u) ? (k & 0x7FFFFFFFu) : ~k);
}

// ---------------- K1: A = emb@W1[:H] ; C = emb@W1[H:] + b1 ----------------
// NUMERICS FROZEN (passed absmax=0 x8) — do not reorder the fma chain.
__global__ __launch_bounds__(H_) void k_ac(const float* __restrict__ emb,
                                           const float* __restrict__ W1,
                                           const float* __restrict__ b1,
                                           float* __restrict__ A,
                                           float* __restrict__ C) {
    __shared__ float e[H_];
    const int i = blockIdx.x;
    const int k = threadIdx.x;
    e[k] = emb[(size_t)i * H_ + k];
    __syncthreads();
    float a = 0.f, c = 0.f;
#pragma unroll 8
    for (int h = 0; h < H_; ++h) {
        const float ev = e[h];
        a = fmaf(ev, W1[h * H_ + k], a);
        c = fmaf(ev, W1[(H_ + h) * H_ + k], c);
    }
    A[(size_t)i * H_ + k] = a;
    C[(size_t)i * H_ + k] = c + b1[k];
}

// ---------------- K2: K[g][i][j] = enc_key(w2 . elu(A_i + C_j) + b2) -------
// z NUMERICS FROZEN: per-value op sequence identical to r1-r9 (8-fma chain in
// h order, then shfl_xor 4/8/16/32, then +b2). C loads are NON-TEMPORAL
// (pure cache hint, bit-identical data) so the 1-2 GB C stream doesn't evict
// K rows from L3 before k_path reads them once each.
__global__ __launch_bounds__(256) void k_z(const float* __restrict__ A,
                                           const float* __restrict__ Cc,
                                           const float* __restrict__ w2,
                                           const float* __restrict__ b2p,
                                           unsigned* __restrict__ K) {
    const int lane = threadIdx.x & 63;
    const int wave = threadIdx.x >> 6;          // 0..3
    const int g = blockIdx.x >> 8;              // 256 blocks per graph
    const int sub = blockIdx.x & 255;
    const int rowtile = sub & 127;
    const int jh = sub >> 7;
    const int ibase = rowtile * 16 + wave * 4;
    const int i = ibase + (lane & 3);           // this group's row
    const int he = (lane >> 2) * 8;             // h-slice start (0..120)
    const float b2v = *b2p;

    const float* Arow = A + ((size_t)g * N_ + i) * H_ + he;
    const float4 a0 = *(const float4*)(Arow);
    const float4 a1 = *(const float4*)(Arow + 4);
    const float4 w0 = *(const float4*)(w2 + he);
    const float4 w1v = *(const float4*)(w2 + he + 4);
    const float* Cg = Cc + (size_t)g * N_ * H_ + he;
    unsigned* Krow = K + ((size_t)g * N_ + i) * N_;
    const bool writer = ((lane >> 2) == 0);

    const int j0 = jh * 1024;
    for (int j = j0; j < j0 + 1024; j += 8) {
        f4v c0[8], c1[8];
#pragma unroll
        for (int q = 0; q < 8; ++q) {
            const float* Cj = Cg + (size_t)(j + q) * H_;
            c0[q] = __builtin_nontemporal_load((const f4v*)(Cj));
            c1[q] = __builtin_nontemporal_load((const f4v*)(Cj + 4));
        }
        float pv[8];
#pragma unroll
        for (int q = 0; q < 8; ++q) {
            float p = 0.f;
            p = fmaf(w0.x, elu1(a0.x + c0[q].x), p);
            p = fmaf(w0.y, elu1(a0.y + c0[q].y), p);
            p = fmaf(w0.z, elu1(a0.z + c0[q].z), p);
            p = fmaf(w0.w, elu1(a0.w + c0[q].w), p);
            p = fmaf(w1v.x, elu1(a1.x + c1[q].x), p);
            p = fmaf(w1v.y, elu1(a1.y + c1[q].y), p);
            p = fmaf(w1v.z, elu1(a1.z + c1[q].z), p);
            p = fmaf(w1v.w, elu1(a1.w + c1[q].w), p);
            pv[q] = p;
        }
        // 8 independent shuffle-reduce chains (same per-value order as r1-r9)
#pragma unroll
        for (int q = 0; q < 8; ++q) pv[q] += __shfl_xor(pv[q], 4);
#pragma unroll
        for (int q = 0; q < 8; ++q) pv[q] += __shfl_xor(pv[q], 8);
#pragma unroll
        for (int q = 0; q < 8; ++q) pv[q] += __shfl_xor(pv[q], 16);
#pragma unroll
        for (int q = 0; q < 8; ++q) pv[q] += __shfl_xor(pv[q], 32);
        if (writer) {
            uint4 ka, kb;
            ka.x = enc_key(pv[0] + b2v);
            ka.y = enc_key(pv[1] + b2v);
            ka.z = enc_key(pv[2] + b2v);
            ka.w = enc_key(pv[3] + b2v);
            kb.x = enc_key(pv[4] + b2v);
            kb.y = enc_key(pv[5] + b2v);
            kb.z = enc_key(pv[6] + b2v);
            kb.w = enc_key(pv[7] + b2v);
            *(uint4*)(Krow + j) = ka;
            *(uint4*)(Krow + j + 4) = kb;
        }
    }
}

// ---------------- K3: greedy chain — 256-thread walker, shallow reduce -----
// Thread tid owns slots j = 8*tid .. 8*tid+7 (two uint4 loads). Visited mask
// = 8-bit register. Reduce: depth-3 in-lane tree (strict > keeps min j) ->
// 6-round lexicographic wave butterfly -> one barrier -> every thread folds
// the 4 wave partials from LDS (parity double-buffered; no 2nd barrier).
// Next-row loads issue before sigmoid/break so HBM/L3 latency overlaps them.
__global__ __launch_bounds__(256) void k_path7(const float* __restrict__ emb,
                                               const unsigned* __restrict__ K,
                                               float* __restrict__ out) {
    const int g = blockIdx.x;
    const int tid = threadIdx.x;       // 0..255
    const int lane = tid & 63;
    const int wid = tid >> 6;          // 0..3

    __shared__ unsigned swv[2][4];
    __shared__ int swj[2][4];
    __shared__ int s_root;

    float* pathOut = out + (size_t)g * N_;
    float* scoreOut = out + (size_t)BN_ + (size_t)g * N_;

    // root = argmax_j emb[g][j][0], first-max tie-break (wave 0 only)
    if (tid < 64) {
        float bv0 = -INFINITY;
        int bi0 = 0x7fffffff;
        for (int j = lane; j < N_; j += 64) {
            const float v = emb[((size_t)g * N_ + j) * H_];
            if (v > bv0) { bv0 = v; bi0 = j; }  // ascending j => first max
        }
#pragma unroll
        for (int off = 1; off < 64; off <<= 1) {
            const float ov = __shfl_xor(bv0, off);
            const int oi = __shfl_xor(bi0, off);
            if (ov > bv0 || (ov == bv0 && oi < bi0)) { bv0 = ov; bi0 = oi; }
        }
        if (lane == 0) {
            s_root = bi0;
            pathOut[0] = (float)bi0;
            scoreOut[0] = 1.0f;
        }
    }
    __syncthreads();

    int cur = s_root;
    unsigned vb = 0;
    if ((cur >> 3) == tid) vb |= 1u << (cur & 7);

    const unsigned* Kg = K + (size_t)g * N_ * N_;
    uint4 k0, k1;
    {
        const uint4* p = (const uint4*)(Kg + ((size_t)cur << 11) + (tid << 3));
        k0 = p[0];
        k1 = p[1];
    }

    int par = 0;
    int t = 1;
    for (; t < N_; ++t) {
        // mask visited -> 0 (finite keys never 0)
        const unsigned v0 = (vb & 1u)   ? 0u : k0.x;
        const unsigned v1 = (vb & 2u)   ? 0u : k0.y;
        const unsigned v2 = (vb & 4u)   ? 0u : k0.z;
        const unsigned v3 = (vb & 8u)   ? 0u : k0.w;
        const unsigned v4 = (vb & 16u)  ? 0u : k1.x;
        const unsigned v5 = (vb & 32u)  ? 0u : k1.y;
        const unsigned v6 = (vb & 64u)  ? 0u : k1.z;
        const unsigned v7 = (vb & 128u) ? 0u : k1.w;

        // depth-3 tree; strict > keeps the lower slot (min j) on ties
        unsigned va = v0; int ja = 0;
        if (v1 > va) { va = v1; ja = 1; }
        unsigned vbp = v2; int jb = 2;
        if (v3 > vbp) { vbp = v3; jb = 3; }
        unsigned vc = v4; int jc = 4;
        if (v5 > vc) { vc = v5; jc = 5; }
        unsigned vd = v6; int jd = 6;
        if (v7 > vd) { vd = v7; jd = 7; }
        if (vbp > va) { va = vbp; ja = jb; }
        if (vd > vc) { vc = vd; jc = jd; }
        if (vc > va) { va = vc; ja = jc; }
        unsigned wv_ = va;
        int wj_ = (tid << 3) | ja;

        // 6-round lexicographic wave butterfly: (max key, min j)
#pragma unroll
        for (int off = 1; off < 64; off <<= 1) {
            const unsigned ov = __shfl_xor(wv_, off);
            const int oj = __shfl_xor(wj_, off);
            if (ov > wv_ || (ov == wv_ && oj < wj_)) { wv_ = ov; wj_ = oj; }
        }
        if (lane == 0) {
            swv[par][wid] = wv_;
            swj[par][wid] = wj_;
        }
        __syncthreads();

        // serial-redundant fold of the 4 wave partials (every thread)
        unsigned fv = swv[par][0];
        int fj = swj[par][0];
#pragma unroll
        for (int w = 1; w < 4; ++w) {
            const unsigned nv = swv[par][w];
            const int nj = swj[par][w];
            if (nv > fv || (nv == fv && nj < fj)) { fv = nv; fj = nj; }
        }
        const int bi = fj;

        // issue next row's loads NOW; sigmoid/break/bookkeeping overlap them
        uint4 n0, n1;
        {
            const uint4* p = (const uint4*)(Kg + ((size_t)bi << 11) + (tid << 3));
            n0 = p[0];
            n1 = p[1];
        }

        const float bv = dec_key(fv);
        const float s = 1.f / (1.f + expf(-bv));
        if (!((double)s > 0.3)) break;  // frozen break form (passed r1-r9)
        if ((bi >> 3) == tid) vb |= 1u << (bi & 7);
        if (tid == 0) {
            pathOut[t] = (float)bi;
            scoreOut[t] = s;
        }
        k0 = n0;
        k1 = n1;
        par ^= 1;
    }
    for (int tt = t + tid; tt < N_; tt += 256) {
        pathOut[tt] = -1.f;
        scoreOut[tt] = 0.f;
    }
}

// ---------------- Fallback: on-the-fly scoring (ws too small for K) --------
__device__ __forceinline__ void blockArgmax(float& bv, int& bi, float* rv, int* ri,
                                            int lane, int wid, int nw) {
#pragma unroll
    for (int off = 1; off < 64; off <<= 1) {
        const float ov = __shfl_xor(bv, off);
        const int oi = __shfl_xor(bi, off);
        if (ov > bv || (ov == bv && oi < bi)) { bv = ov; bi = oi; }
    }
    if (lane == 0) { rv[wid] = bv; ri[wid] = bi; }
    __syncthreads();
    if (wid == 0) {
        float v = (lane < nw) ? rv[lane] : -INFINITY;
        int ix = (lane < nw) ? ri[lane] : 0x7fffffff;
#pragma unroll
        for (int off = 1; off < 16; off <<= 1) {
            const float ov = __shfl_xor(v, off);
            const int oi = __shfl_xor(ix, off);
            if (ov > v || (ov == v && oi < ix)) { v = ov; ix = oi; }
        }
        if (lane == 0) { rv[0] = v; ri[0] = ix; }
    }
    __syncthreads();
    bv = rv[0];
    bi = ri[0];
}

__global__ __launch_bounds__(1024) void k_path_fly(const float* __restrict__ emb,
                                                   const float* __restrict__ A,
                                                   const float* __restrict__ Cc,
                                                   const float* __restrict__ w2g,
                                                   const float* __restrict__ b2p,
                                                   float* __restrict__ out) {
    const int g = blockIdx.x;
    const int tid = threadIdx.x;
    const int lane = tid & 63, wid = tid >> 6;
    __shared__ float acur[H_], w2s[H_];
    __shared__ unsigned char vis[N_];
    __shared__ float rv[16];
    __shared__ int ri[16];
    const float b2v = *b2p;
    if (tid < H_) w2s[tid] = w2g[tid];
    for (int j = tid; j < N_; j += 1024) vis[j] = 0;

    float bv = -INFINITY;
    int bi = 0x7fffffff;
    for (int j = tid; j < N_; j += 1024) {
        const float v = emb[((size_t)g * N_ + j) * H_];
        if (v > bv) { bv = v; bi = j; }
    }
    __syncthreads();
    blockArgmax(bv, bi, rv, ri, lane, wid, 16);
    int cur = bi;
    float* pathOut = out + (size_t)g * N_;
    float* scoreOut = out + (size_t)BN_ + (size_t)g * N_;
    if (tid == 0) {
        vis[cur] = 1;
        pathOut[0] = (float)cur;
        scoreOut[0] = 1.0f;
    }
    __syncthreads();

    int t = 1;
    for (; t < N_; ++t) {
        if (tid < H_) acur[tid] = A[((size_t)g * N_ + cur) * H_ + tid];
        __syncthreads();
        float mbv = -INFINITY;
        int mbi = 0x7fffffff;
#pragma unroll
        for (int q = 0; q < 2; ++q) {
            const int j = tid + q * 1024;
            const float* Cj = Cc + ((size_t)g * N_ + j) * H_;
            float p = 0.f;
            for (int h = 0; h < H_; h += 4) {
                const float4 c = *(const float4*)(Cj + h);
                p = fmaf(w2s[h + 0], elu1(acur[h + 0] + c.x), p);
                p = fmaf(w2s[h + 1], elu1(acur[h + 1] + c.y), p);
                p = fmaf(w2s[h + 2], elu1(acur[h + 2] + c.z), p);
                p = fmaf(w2s[h + 3], elu1(acur[h + 3] + c.w), p);
            }
            const float z = p + b2v;
            if (!vis[j] && (z > mbv || (z == mbv && j < mbi))) { mbv = z; mbi = j; }
        }
        __syncthreads();
        blockArgmax(mbv, mbi, rv, ri, lane, wid, 16);
        const float s = 1.f / (1.f + expf(-mbv));
        if (!((double)s > 0.3)) break;
        cur = mbi;
        if (tid == 0) {
            vis[cur] = 1;
            pathOut[t] = (float)cur;
            scoreOut[t] = s;
        }
        __syncthreads();
    }
    for (int tt = t + tid; tt < N_; tt += 1024) {
        pathOut[tt] = -1.f;
        scoreOut[tt] = 0.f;
    }
}

extern "C" void kernel_launch(void* const* d_in, const int* in_sizes, int n_in,
                              void* d_out, int out_size, void* d_ws, size_t ws_size,
                              hipStream_t stream) {
    (void)in_sizes; (void)n_in; (void)out_size;
    const float* emb = (const float*)d_in[0];
    // d_in[1] = batch (int64) — contiguous equal-sized graphs, unused
    const float* W1 = (const float*)d_in[2];
    const float* b1 = (const float*)d_in[3];
    const float* w2 = (const float*)d_in[4];
    const float* b2 = (const float*)d_in[5];
    float* out = (float*)d_out;

    float* A = (float*)d_ws;
    float* C = A + (size_t)BN_ * H_;
    unsigned* K = (unsigned*)(C + (size_t)BN_ * H_);
    const size_t need = ((size_t)BN_ * H_ * 2 + (size_t)B_ * N_ * N_) * sizeof(float);

    hipLaunchKernelGGL(k_ac, dim3(BN_), dim3(H_), 0, stream, emb, W1, b1, A, C);
    if (ws_size >= need) {
        hipLaunchKernelGGL(k_z, dim3(2048), dim3(256), 0, stream, A, C, w2, b2, K);
        hipLaunchKernelGGL(k_path7, dim3(B_), dim3(256), 0, stream, emb, K, out);
    } else {
        hipLaunchKernelGGL(k_path_fly, dim3(B_), dim3(1024), 0, stream,
                           emb, A, C, w2, b2, out);
    }
}

// Round 13
// 3066.778 us; speedup vs baseline: 1.2566x; 1.2552x over previous
//
#include <hip/hip_runtime.h>
#include <math.h>

#define B_ 8
#define N_ 2048
#define H_ 128
#define BN_ (B_ * N_)

// ws layout: A [BN][H] f32 | C [BN][H] f32 | K [B][N][N] u32 (sortable keys)
// need = 2*8MB + 128MB = 150,994,944 bytes

typedef int i32x2 __attribute__((ext_vector_type(2)));

__device__ __forceinline__ float elu1(float x) {
    return x > 0.f ? x : (__expf(x) - 1.f);
}

// Order-preserving bijection f32 -> u32 (exact inverse). Finite floats never map to 0.
__device__ __forceinline__ unsigned enc_key(float v) {
    unsigned u = __float_as_uint(v);
    return (u & 0x80000000u) ? ~u : (u | 0x80000000u);
}
__device__ __forceinline__ float dec_key(unsigned k) {
    return __uint_as_float((k & 0x80000000u) ? (k & 0x7FFFFFFFu) : ~k);
}
__device__ __forceinline__ unsigned umax2(unsigned a, unsigned b) { return a > b ? a : b; }

// Wave-wide u32 max on the VALU pipe: DPP (xor1, xor2, ror4, ror8 within each
// 16-lane row) + permlane16/32_swap for the row crossings. Rotations are valid
// for an idempotent all-reduce; after ror4+ror8 every lane holds its row max.
__device__ __forceinline__ unsigned wave_umax64(unsigned x) {
    unsigned t;
    t = (unsigned)__builtin_amdgcn_update_dpp((int)x, (int)x, 0xB1, 0xF, 0xF, false);  // quad_perm [1,0,3,2]
    x = umax2(x, t);
    t = (unsigned)__builtin_amdgcn_update_dpp((int)x, (int)x, 0x4E, 0xF, 0xF, false);  // quad_perm [2,3,0,1]
    x = umax2(x, t);
    t = (unsigned)__builtin_amdgcn_update_dpp((int)x, (int)x, 0x124, 0xF, 0xF, false); // row_ror:4
    x = umax2(x, t);
    t = (unsigned)__builtin_amdgcn_update_dpp((int)x, (int)x, 0x128, 0xF, 0xF, false); // row_ror:8
    x = umax2(x, t);
#if __has_builtin(__builtin_amdgcn_permlane16_swap)
    {
        i32x2 r = __builtin_amdgcn_permlane16_swap((int)x, (int)x, false, false);
        x = umax2((unsigned)r.x, (unsigned)r.y);
    }
#else
    x = umax2(x, (unsigned)__shfl_xor((int)x, 16));
#endif
#if __has_builtin(__builtin_amdgcn_permlane32_swap)
    {
        i32x2 r = __builtin_amdgcn_permlane32_swap((int)x, (int)x, false, false);
        x = umax2((unsigned)r.x, (unsigned)r.y);
    }
#else
    x = umax2(x, (unsigned)__shfl_xor((int)x, 32));
#endif
    return x;
}

// ---------------- K1: A = emb@W1[:H] ; C = emb@W1[H:] + b1 ----------------
// NUMERICS FROZEN (passed absmax=0 x10) — do not reorder the fma chain.
__global__ __launch_bounds__(H_) void k_ac(const float* __restrict__ emb,
                                           const float* __restrict__ W1,
                                           const float* __restrict__ b1,
                                           float* __restrict__ A,
                                           float* __restrict__ C) {
    __shared__ float e[H_];
    const int i = blockIdx.x;
    const int k = threadIdx.x;
    e[k] = emb[(size_t)i * H_ + k];
    __syncthreads();
    float a = 0.f, c = 0.f;
#pragma unroll 8
    for (int h = 0; h < H_; ++h) {
        const float ev = e[h];
        a = fmaf(ev, W1[h * H_ + k], a);
        c = fmaf(ev, W1[(H_ + h) * H_ + k], c);
    }
    A[(size_t)i * H_ + k] = a;
    C[(size_t)i * H_ + k] = c + b1[k];
}

// ---------------- K2: K[g][i][j] = enc_key(w2 . elu(A_i + C_j) + b2) -------
// z NUMERICS FROZEN: per-value op sequence identical to r1-r12 (8-fma chain in
// h order, then shfl_xor 4/8/16/32, then +b2). NT hint reverted (r12: no effect).
__global__ __launch_bounds__(256) void k_z(const float* __restrict__ A,
                                           const float* __restrict__ Cc,
                                           const float* __restrict__ w2,
                                           const float* __restrict__ b2p,
                                           unsigned* __restrict__ K) {
    const int lane = threadIdx.x & 63;
    const int wave = threadIdx.x >> 6;          // 0..3
    const int g = blockIdx.x >> 8;              // 256 blocks per graph
    const int sub = blockIdx.x & 255;
    const int rowtile = sub & 127;
    const int jh = sub >> 7;
    const int ibase = rowtile * 16 + wave * 4;
    const int i = ibase + (lane & 3);           // this group's row
    const int he = (lane >> 2) * 8;             // h-slice start (0..120)
    const float b2v = *b2p;

    const float* Arow = A + ((size_t)g * N_ + i) * H_ + he;
    const float4 a0 = *(const float4*)(Arow);
    const float4 a1 = *(const float4*)(Arow + 4);
    const float4 w0 = *(const float4*)(w2 + he);
    const float4 w1v = *(const float4*)(w2 + he + 4);
    const float* Cg = Cc + (size_t)g * N_ * H_ + he;
    unsigned* Krow = K + ((size_t)g * N_ + i) * N_;
    const bool writer = ((lane >> 2) == 0);

    const int j0 = jh * 1024;
    for (int j = j0; j < j0 + 1024; j += 8) {
        float4 c0[8], c1[8];
#pragma unroll
        for (int q = 0; q < 8; ++q) {
            const float* Cj = Cg + (size_t)(j + q) * H_;
            c0[q] = *(const float4*)(Cj);
            c1[q] = *(const float4*)(Cj + 4);
        }
        float pv[8];
#pragma unroll
        for (int q = 0; q < 8; ++q) {
            float p = 0.f;
            p = fmaf(w0.x, elu1(a0.x + c0[q].x), p);
            p = fmaf(w0.y, elu1(a0.y + c0[q].y), p);
            p = fmaf(w0.z, elu1(a0.z + c0[q].z), p);
            p = fmaf(w0.w, elu1(a0.w + c0[q].w), p);
            p = fmaf(w1v.x, elu1(a1.x + c1[q].x), p);
            p = fmaf(w1v.y, elu1(a1.y + c1[q].y), p);
            p = fmaf(w1v.z, elu1(a1.z + c1[q].z), p);
            p = fmaf(w1v.w, elu1(a1.w + c1[q].w), p);
            pv[q] = p;
        }
        // 8 independent shuffle-reduce chains (same per-value order as r1-r12)
#pragma unroll
        for (int q = 0; q < 8; ++q) pv[q] += __shfl_xor(pv[q], 4);
#pragma unroll
        for (int q = 0; q < 8; ++q) pv[q] += __shfl_xor(pv[q], 8);
#pragma unroll
        for (int q = 0; q < 8; ++q) pv[q] += __shfl_xor(pv[q], 16);
#pragma unroll
        for (int q = 0; q < 8; ++q) pv[q] += __shfl_xor(pv[q], 32);
        if (writer) {
            uint4 ka, kb;
            ka.x = enc_key(pv[0] + b2v);
            ka.y = enc_key(pv[1] + b2v);
            ka.z = enc_key(pv[2] + b2v);
            ka.w = enc_key(pv[3] + b2v);
            kb.x = enc_key(pv[4] + b2v);
            kb.y = enc_key(pv[5] + b2v);
            kb.z = enc_key(pv[6] + b2v);
            kb.w = enc_key(pv[7] + b2v);
            *(uint4*)(Krow + j) = ka;
            *(uint4*)(Krow + j + 4) = kb;
        }
    }
}

// ---------------- K3: greedy chain — DPP butterfly, tree reduce ------------
// Slot s (0..31) of lane L holds j = (s>>2)*256 + 4L + (s&3). Visited -> key 0.
// Value-only tree (depth 5) -> VALU-pipe wave max -> ballot index recovery
// (single-lane fast path; exact min-j tie butterfly otherwise).
__global__ __launch_bounds__(64, 1) void k_path8(const float* __restrict__ emb,
                                                 const unsigned* __restrict__ K,
                                                 float* __restrict__ out) {
    const int g = blockIdx.x;
    const int lane = threadIdx.x;  // 0..63

    // root = argmax_j emb[g][j][0], first-max tie-break
    float bv0 = -INFINITY;
    int bi0 = 0x7fffffff;
    for (int j = lane; j < N_; j += 64) {
        const float v = emb[((size_t)g * N_ + j) * H_];
        if (v > bv0) { bv0 = v; bi0 = j; }  // ascending j per lane => first max
    }
#pragma unroll
    for (int off = 1; off < 64; off <<= 1) {
        const float ov = __shfl_xor(bv0, off);
        const int oi = __shfl_xor(bi0, off);
        if (ov > bv0 || (ov == bv0 && oi < bi0)) { bv0 = ov; bi0 = oi; }
    }
    int cur = bi0;
    unsigned vbits = 0;
    if (((cur >> 2) & 63) == lane)
        vbits |= 1u << (((cur >> 8) << 2) | (cur & 3));

    float* pathOut = out + (size_t)g * N_;
    float* scoreOut = out + (size_t)BN_ + (size_t)g * N_;
    if (lane == 0) {
        pathOut[0] = (float)cur;
        scoreOut[0] = 1.0f;
    }

    const unsigned* Kg = K + (size_t)g * N_ * N_;
    uint4 z[8];
    {
        const uint4* Kr = (const uint4*)(Kg + ((size_t)cur << 11));
#pragma unroll
        for (int k = 0; k < 8; ++k) z[k] = Kr[k * 64 + lane];
    }

    int t = 1;
    for (; t < N_; ++t) {
        // branchless visited mask: kv = raw & (bit - 1)   (bit in {0,1})
        unsigned kv[32];
#define MASK(S, RAW) kv[S] = (RAW) & (((vbits >> (S)) & 1u) - 1u);
        MASK(0,  z[0].x) MASK(1,  z[0].y) MASK(2,  z[0].z) MASK(3,  z[0].w)
        MASK(4,  z[1].x) MASK(5,  z[1].y) MASK(6,  z[1].z) MASK(7,  z[1].w)
        MASK(8,  z[2].x) MASK(9,  z[2].y) MASK(10, z[2].z) MASK(11, z[2].w)
        MASK(12, z[3].x) MASK(13, z[3].y) MASK(14, z[3].z) MASK(15, z[3].w)
        MASK(16, z[4].x) MASK(17, z[4].y) MASK(18, z[4].z) MASK(19, z[4].w)
        MASK(20, z[5].x) MASK(21, z[5].y) MASK(22, z[5].z) MASK(23, z[5].w)
        MASK(24, z[6].x) MASK(25, z[6].y) MASK(26, z[6].z) MASK(27, z[6].w)
        MASK(28, z[7].x) MASK(29, z[7].y) MASK(30, z[7].z) MASK(31, z[7].w)
#undef MASK

        // in-lane value-only max tree (depth 5, ILP-wide)
        unsigned m16[16];
#pragma unroll
        for (int i = 0; i < 16; ++i) m16[i] = umax2(kv[i], kv[i + 16]);
        unsigned m8[8];
#pragma unroll
        for (int i = 0; i < 8; ++i) m8[i] = umax2(m16[i], m16[i + 8]);
        unsigned m4[4];
#pragma unroll
        for (int i = 0; i < 4; ++i) m4[i] = umax2(m8[i], m8[i + 4]);
        const unsigned lanemax =
            umax2(umax2(m4[0], m4[1]), umax2(m4[2], m4[3]));

        // cross-lane max on the VALU pipe (no ds_bpermute)
        const unsigned w = wave_umax64(lanemax);

        // index recovery: per-lane match mask (4 independent or-chains)
        unsigned ma = 0, mb = 0, mc = 0, md = 0;
#pragma unroll
        for (int s = 0; s < 8; ++s) {
            ma |= (kv[s] == w) ? (1u << s) : 0u;
            mb |= (kv[s + 8] == w) ? (1u << (s + 8)) : 0u;
            mc |= (kv[s + 16] == w) ? (1u << (s + 16)) : 0u;
            md |= (kv[s + 24] == w) ? (1u << (s + 24)) : 0u;
        }
        const unsigned mm = (ma | mb) | (mc | md);
        const unsigned long long mk = __ballot(mm != 0u);
        int bi;
        if (__popcll(mk) == 1) {
            const int src = (int)(__ffsll((long long)mk) - 1);
            const unsigned mmw = __shfl(mm, src);
            const int slot = __ffs(mmw) - 1;   // min slot == min j within lane
            bi = ((slot >> 2) << 8) | (src << 2) | (slot & 3);
        } else {
            // rare: equal keys on multiple lanes -> exact min-j via max(~j)
            unsigned cand = 0u;
            if (mm) {
                const int slot = __ffs(mm) - 1;
                cand = ~(unsigned)(((slot >> 2) << 8) | (lane << 2) | (slot & 3));
            }
#pragma unroll
            for (int off = 1; off < 64; off <<= 1) {
                const unsigned oc = __shfl_xor(cand, off);
                if (oc > cand) cand = oc;
            }
            bi = (int)(~cand);
        }

        // issue next row's loads NOW; sigmoid/break/output overlap the latency
        {
            const uint4* Kr = (const uint4*)(Kg + ((size_t)bi << 11));
#pragma unroll
            for (int k = 0; k < 8; ++k) z[k] = Kr[k * 64 + lane];
        }

        const float bv = dec_key(w);
        const float s = 1.f / (1.f + expf(-bv));
        if (!((double)s > 0.3)) break;  // frozen break form (passed r1-r12)
        cur = bi;
        if (((cur >> 2) & 63) == lane)
            vbits |= 1u << (((cur >> 8) << 2) | (cur & 3));
        if (lane == 0) {
            pathOut[t] = (float)cur;
            scoreOut[t] = s;
        }
    }
    for (int tt = t + lane; tt < N_; tt += 64) {
        pathOut[tt] = -1.f;
        scoreOut[tt] = 0.f;
    }
}

// ---------------- Fallback: on-the-fly scoring (ws too small for K) --------
__device__ __forceinline__ void blockArgmax(float& bv, int& bi, float* rv, int* ri,
                                            int lane, int wid, int nw) {
#pragma unroll
    for (int off = 1; off < 64; off <<= 1) {
        const float ov = __shfl_xor(bv, off);
        const int oi = __shfl_xor(bi, off);
        if (ov > bv || (ov == bv && oi < bi)) { bv = ov; bi = oi; }
    }
    if (lane == 0) { rv[wid] = bv; ri[wid] = bi; }
    __syncthreads();
    if (wid == 0) {
        float v = (lane < nw) ? rv[lane] : -INFINITY;
        int ix = (lane < nw) ? ri[lane] : 0x7fffffff;
#pragma unroll
        for (int off = 1; off < 16; off <<= 1) {
            const float ov = __shfl_xor(v, off);
            const int oi = __shfl_xor(ix, off);
            if (ov > v || (ov == v && oi < ix)) { v = ov; ix = oi; }
        }
        if (lane == 0) { rv[0] = v; ri[0] = ix; }
    }
    __syncthreads();
    bv = rv[0];
    bi = ri[0];
}

__global__ __launch_bounds__(1024) void k_path_fly(const float* __restrict__ emb,
                                                   const float* __restrict__ A,
                                                   const float* __restrict__ Cc,
                                                   const float* __restrict__ w2g,
                                                   const float* __restrict__ b2p,
                                                   float* __restrict__ out) {
    const int g = blockIdx.x;
    const int tid = threadIdx.x;
    const int lane = tid & 63, wid = tid >> 6;
    __shared__ float acur[H_], w2s[H_];
    __shared__ unsigned char vis[N_];
    __shared__ float rv[16];
    __shared__ int ri[16];
    const float b2v = *b2p;
    if (tid < H_) w2s[tid] = w2g[tid];
    for (int j = tid; j < N_; j += 1024) vis[j] = 0;

    float bv = -INFINITY;
    int bi = 0x7fffffff;
    for (int j = tid; j < N_; j += 1024) {
        const float v = emb[((size_t)g * N_ + j) * H_];
        if (v > bv) { bv = v; bi = j; }
    }
    __syncthreads();
    blockArgmax(bv, bi, rv, ri, lane, wid, 16);
    int cur = bi;
    float* pathOut = out + (size_t)g * N_;
    float* scoreOut = out + (size_t)BN_ + (size_t)g * N_;
    if (tid == 0) {
        vis[cur] = 1;
        pathOut[0] = (float)cur;
        scoreOut[0] = 1.0f;
    }
    __syncthreads();

    int t = 1;
    for (; t < N_; ++t) {
        if (tid < H_) acur[tid] = A[((size_t)g * N_ + cur) * H_ + tid];
        __syncthreads();
        float mbv = -INFINITY;
        int mbi = 0x7fffffff;
#pragma unroll
        for (int q = 0; q < 2; ++q) {
            const int j = tid + q * 1024;
            const float* Cj = Cc + ((size_t)g * N_ + j) * H_;
            float p = 0.f;
            for (int h = 0; h < H_; h += 4) {
                const float4 c = *(const float4*)(Cj + h);
                p = fmaf(w2s[h + 0], elu1(acur[h + 0] + c.x), p);
                p = fmaf(w2s[h + 1], elu1(acur[h + 1] + c.y), p);
                p = fmaf(w2s[h + 2], elu1(acur[h + 2] + c.z), p);
                p = fmaf(w2s[h + 3], elu1(acur[h + 3] + c.w), p);
            }
            const float z = p + b2v;
            if (!vis[j] && (z > mbv || (z == mbv && j < mbi))) { mbv = z; mbi = j; }
        }
        __syncthreads();
        blockArgmax(mbv, mbi, rv, ri, lane, wid, 16);
        const float s = 1.f / (1.f + expf(-mbv));
        if (!((double)s > 0.3)) break;
        cur = mbi;
        if (tid == 0) {
            vis[cur] = 1;
            pathOut[t] = (float)cur;
            scoreOut[t] = s;
        }
        __syncthreads();
    }
    for (int tt = t + tid; tt < N_; tt += 1024) {
        pathOut[tt] = -1.f;
        scoreOut[tt] = 0.f;
    }
}

extern "C" void kernel_launch(void* const* d_in, const int* in_sizes, int n_in,
                              void* d_out, int out_size, void* d_ws, size_t ws_size,
                              hipStream_t stream) {
    (void)in_sizes; (void)n_in; (void)out_size;
    const float* emb = (const float*)d_in[0];
    // d_in[1] = batch (int64) — contiguous equal-sized graphs, unused
    const float* W1 = (const float*)d_in[2];
    const float* b1 = (const float*)d_in[3];
    const float* w2 = (const float*)d_in[4];
    const float* b2 = (const float*)d_in[5];
    float* out = (float*)d_out;

    float* A = (float*)d_ws;
    float* C = A + (size_t)BN_ * H_;
    unsigned* K = (unsigned*)(C + (size_t)BN_ * H_);
    const size_t need = ((size_t)BN_ * H_ * 2 + (size_t)B_ * N_ * N_) * sizeof(float);

    hipLaunchKernelGGL(k_ac, dim3(BN_), dim3(H_), 0, stream, emb, W1, b1, A, C);
    if (ws_size >= need) {
        hipLaunchKernelGGL(k_z, dim3(2048), dim3(256), 0, stream, A, C, w2, b2, K);
        hipLaunchKernelGGL(k_path8, dim3(B_), dim3(64), 0, stream, emb, K, out);
    } else {
        hipLaunchKernelGGL(k_path_fly, dim3(B_), dim3(1024), 0, stream,
                           emb, A, C, w2, b2, out);
    }
}